// Round 5
// baseline (14525.764 us; speedup 1.0000x reference)
//
#include <hip/hip_runtime.h>
#include <math.h>
#include <stdint.h>

#define D       128
#define KCODES  1024
#define NQ      8
#define BATCH   8
#define SLEN    4096
#define NPTS    (BATCH*SLEN)     /* 32768 */
#define TM      64               /* points per argmin unit */
#define NUNITS  1024             /* 512 point-blocks x 2 code-halves */

// async global->LDS, 16B per lane (wave-uniform LDS base + lane*16)
typedef __attribute__((address_space(1))) const void GV;
typedef __attribute__((address_space(3))) void LV;
__device__ __forceinline__ void gload16(const void* g, void* l) {
    __builtin_amdgcn_global_load_lds((GV*)g, (LV*)l, 16, 0, 0);
}

// ---------------- zero scratch ----------------
__global__ void k_zero(int* hist, double* csum, int* ctr) {
    int t = blockIdx.x * blockDim.x + threadIdx.x;
    if (t < NQ * KCODES) hist[t] = 0;
    if (t < NQ) ctr[t] = 0;
    if (t == 0) *csum = 0.0;
}

// ---------------- codebook norms: numpy pairwise fp32 ----------------
__global__ void k_c2(const float* __restrict__ cbs, float* __restrict__ c2f) {
    int i = blockIdx.x * blockDim.x + threadIdx.x;   // 0..8191
    const float* row = cbs + (size_t)i * D;
    float r8[8];
    #pragma unroll
    for (int j = 0; j < 8; ++j) r8[j] = __fmul_rn(row[j], row[j]);
    for (int d = 8; d < 128; d += 8)
        #pragma unroll
        for (int j = 0; j < 8; ++j)
            r8[j] = __fadd_rn(r8[j], __fmul_rn(row[d + j], row[d + j]));
    float s01 = __fadd_rn(r8[0], r8[1]);
    float s23 = __fadd_rn(r8[2], r8[3]);
    float s45 = __fadd_rn(r8[4], r8[5]);
    float s67 = __fadd_rn(r8[6], r8[7]);
    c2f[i] = __fadd_rn(__fadd_rn(s01, s23), __fadd_rn(s45, s67));
}

// ---------------- init: z [B,D,S] -> resid fp32 [n][d]; quant = 0 ----------------
__global__ __launch_bounds__(256) void k_init(const float* __restrict__ z,
                                              float* __restrict__ resid,
                                              float* __restrict__ quant) {
    __shared__ float xt[64][129];
    int b = blockIdx.x >> 6, st = blockIdx.x & 63;
    int s0 = st * 64;
    for (int it = 0; it < 32; ++it) {
        int flat = it * 256 + threadIdx.x;
        int d = flat >> 6, sl = flat & 63;
        xt[sl][d] = z[((size_t)(b * D + d)) * SLEN + s0 + sl];
    }
    __syncthreads();
    for (int it = 0; it < 8; ++it) {
        int flat = it * 256 + threadIdx.x;
        int sl = flat >> 5, dq = (flat & 31) * 4;
        size_t o = (size_t)(b * SLEN + s0 + sl) * D + dq;
        float4 r;
        r.x = xt[sl][dq]; r.y = xt[sl][dq + 1];
        r.z = xt[sl][dq + 2]; r.w = xt[sl][dq + 3];
        *(float4*)(resid + o) = r;
        float4 zz; zz.x = zz.y = zz.z = zz.w = 0.0f;
        *(float4*)(quant + o) = zz;
    }
}

// ---------------- fp32-emulated argmin (matches numpy/BLAS rounding) ----------------
// r5 = r4 + race fix. Persistent blocks + code-split halves, 3 blocks/CU.
// 768 blocks x 256 thr pull units (pblk, half) off an atomic counter.
// Per unit: 64 points x 512 codes. Wave w owns codes half*512+w*128..+128
// (2 chunks of 64). pl=l&7, cl=l>>3; 8x8 tile/thread. Single-buffered
// per-wave 4KB cs, DMA'd via global_load_lds with pre-swizzled source
// (conflict-free cf reads, verified r2: SQ_LDS_BANK_CONFLICT==0).
// Schedule/slice: vmcnt(0); compute(64 ds_read + 1024 FMA); issue next DMA.
// RACE FIX: __syncthreads() BEFORE the reduction scratch (overlaid on xs
// rows 0..3) is written -- in the barrier-free schedule other waves may
// still be reading xs rows 0..7 as X data (this was r4's failure).
// c2 staged by plain load + ds_write (no divergent DMA).
// Exact fp32 semantics: per (point,code) single FMA chain dims 0..127
// ascending; score fl(fl(xx-2*acc)+cc); first-min (strict <, k ascending);
// cross-half merge tie -> lower half (= lower k).
__global__ __launch_bounds__(256, 3) void k_argmin(const float* __restrict__ cb,
                                                   const float* __restrict__ c2,
                                                   const float* __restrict__ resid,
                                                   float* __restrict__ pbest,
                                                   int* __restrict__ pidx,
                                                   int* __restrict__ ctr) {
    __shared__ __align__(16) float xs[TM][132];     // 33,792 B (xx in pad col 128)
    __shared__ __align__(16) float cs[4][1024];     // 16,384 B: per-wave single buf
    __shared__ __align__(16) float ccl[4][128];     //  2,048 B: per-wave c2 slice
    __shared__ int s_u;

    int tid = threadIdx.x;
    int l = tid & 63, w = tid >> 6;
    int pl = l & 7, cl = l >> 3;

    // pre-swizzled per-lane global source offset within one (chunk,slice,g) unit:
    // row l>>2 (+16 per g), fetch dim-chunk (l&3)^tau, tau=((l>>3)&3)==((row>>1)&3)
    int gsrc_lane = ((l >> 2) << 9) + ((((l & 3) ^ ((l >> 3) & 3))) << 4);
    // cf read swizzle: row k'=cl+8j -> tau_row = (cl>>1)&3 (indep of j)
    int rtau = (cl >> 1) & 3;
    char* csw = (char*)&cs[w][0];
    const char* xsb = (const char*)&xs[0][0];
    // reduction scratch overlaid on xs (rows 0..3): 256 floats + 256 ints
    float* redS = &xs[0][0];
    int*   redI = (int*)(redS + 256);

    for (;;) {
        if (tid == 0) s_u = atomicAdd(ctr, 1);
        __syncthreads();                       // s_u visible; prev-unit xs/red done
        int u = s_u;
        if (u >= NUNITS) return;
        int pblk = u >> 1, half = u & 1;
        int pbase = pblk * TM;
        const char* cwb = (const char*)cb + ((size_t)(half * 512 + w * 128) << 9);

        // prologue: slice (c0,s0) DMA; c2 slice via plain load + ds_write
        {
            const char* src = cwb + gsrc_lane;
            gload16(src,             csw);
            gload16(src + (1 << 13), csw + (1 << 10));
            gload16(src + (2 << 13), csw + (2 << 10));
            gload16(src + (3 << 13), csw + (3 << 10));
        }
        if (l < 32) {
            float4 cv = *(const float4*)(c2 + half * 512 + w * 128 + l * 4);
            *(float4*)&ccl[w][l * 4] = cv;
        }

        // stage X tile (fp32 residual), coalesced float4
        #pragma unroll
        for (int it = 0; it < 8; ++it) {
            int e = (it * 256 + tid) * 4;
            int p = e >> 7, d = e & 127;
            *(float4*)&xs[p][d] = *(const float4*)(resid + (size_t)(pbase + p) * D + d);
        }
        __syncthreads();

        // xx per point: numpy pairwise n=128 (8-accumulator pattern); store in pad
        if (tid < TM) {
            float r8[8];
            #pragma unroll
            for (int j = 0; j < 8; ++j) r8[j] = __fmul_rn(xs[tid][j], xs[tid][j]);
            for (int i = 8; i < 128; i += 8)
                #pragma unroll
                for (int j = 0; j < 8; ++j)
                    r8[j] = __fadd_rn(r8[j], __fmul_rn(xs[tid][i + j], xs[tid][i + j]));
            float s01 = __fadd_rn(r8[0], r8[1]);
            float s23 = __fadd_rn(r8[2], r8[3]);
            float s45 = __fadd_rn(r8[4], r8[5]);
            float s67 = __fadd_rn(r8[6], r8[7]);
            xs[tid][128] = __fadd_rn(__fadd_rn(s01, s23), __fadd_rn(s45, s67));
        }
        __syncthreads();

        float xxr[8];
        #pragma unroll
        for (int i = 0; i < 8; ++i) xxr[i] = xs[pl + 8 * i][128];

        float acc[8][8];
        #pragma unroll
        for (int i = 0; i < 8; ++i)
            #pragma unroll
            for (int j = 0; j < 8; ++j) acc[i][j] = 0.0f;
        float best[8]; int bidx[8];
        #pragma unroll
        for (int i = 0; i < 8; ++i) { best[i] = 3.4e38f; bidx[i] = 0; }

        #pragma unroll 1
        for (int c = 0; c < 2; ++c) {
            #pragma unroll 1
            for (int s = 0; s < 8; ++s) {
                asm volatile("s_waitcnt vmcnt(0)" ::: "memory");   // slice arrived
                const char* cbuf = csw + (cl << 6);
                const char* xrow = xsb + pl * 528 + (s << 6);
                #pragma unroll
                for (int d4 = 0; d4 < 4; ++d4) {
                    float4 xf[8];
                    #pragma unroll
                    for (int i = 0; i < 8; ++i)
                        xf[i] = *(const float4*)(xrow + i * 4224 + (d4 << 4));
                    #pragma unroll
                    for (int jb = 0; jb < 2; ++jb) {
                        float4 cf[4];
                        #pragma unroll
                        for (int j = 0; j < 4; ++j)
                            cf[j] = *(const float4*)(cbuf + ((d4 ^ rtau) << 4)
                                                     + ((jb * 4 + j) << 9));
                        #pragma unroll
                        for (int j = 0; j < 4; ++j) {
                            int jj = jb * 4 + j;
                            #pragma unroll
                            for (int i = 0; i < 8; ++i) {
                                acc[i][jj] = __fmaf_rn(xf[i].x, cf[j].x, acc[i][jj]);
                                acc[i][jj] = __fmaf_rn(xf[i].y, cf[j].y, acc[i][jj]);
                                acc[i][jj] = __fmaf_rn(xf[i].z, cf[j].z, acc[i][jj]);
                                acc[i][jj] = __fmaf_rn(xf[i].w, cf[j].w, acc[i][jj]);
                            }
                        }
                    }
                }
                int t = (c << 3) + s;
                if (t < 15) {                  // issue next slice (single buffer:
                    __builtin_amdgcn_sched_barrier(0);   // after reads complete)
                    int t2 = t + 1;
                    const char* src = cwb + gsrc_lane + ((t2 >> 3) << 15)
                                      + ((t2 & 7) << 6);
                    gload16(src,             csw);
                    gload16(src + (1 << 13), csw + (1 << 10));
                    gload16(src + (2 << 13), csw + (2 << 10));
                    gload16(src + (3 << 13), csw + (3 << 10));
                }
            }
            // end of 64-code chunk: fold scores (overlaps next-chunk DMA)
            #pragma unroll
            for (int j = 0; j < 8; ++j) {
                float cc = ccl[w][(c << 6) + cl + (j << 3)];
                int k = half * 512 + (w << 7) + (c << 6) + cl + (j << 3);
                #pragma unroll
                for (int i = 0; i < 8; ++i) {
                    float t1  = __fadd_rn(xxr[i], __fmul_rn(-2.0f, acc[i][j]));
                    float dsc = __fadd_rn(t1, cc);
                    if (dsc < best[i]) { best[i] = dsc; bidx[i] = k; }  // k ascending
                    acc[i][j] = 0.0f;
                }
            }
        }

        // RACE FIX: all waves must finish reading xs before the overlaid
        // reduction scratch (xs rows 0..3) is written.
        __syncthreads();

        // cross-lane (cl) lexicographic argmin reduce, then cross-wave via LDS
        #pragma unroll
        for (int i = 0; i < 8; ++i) {
            float b = best[i]; int bi = bidx[i];
            #pragma unroll
            for (int off = 8; off < 64; off <<= 1) {
                float b2 = __shfl_xor(b, off, 64);
                int  bi2 = __shfl_xor(bi, off, 64);
                if (b2 < b || (b2 == b && bi2 < bi)) { b = b2; bi = bi2; }
            }
            if (cl == 0) { redS[w * TM + pl + 8 * i] = b; redI[w * TM + pl + 8 * i] = bi; }
        }
        __syncthreads();
        if (tid < TM) {
            float b = redS[tid]; int bi = redI[tid];
            #pragma unroll
            for (int ww = 1; ww < 4; ++ww) {
                float b2 = redS[ww * TM + tid]; int bi2 = redI[ww * TM + tid];
                if (b2 < b || (b2 == b && bi2 < bi)) { b = b2; bi = bi2; }
            }
            pbest[half * NPTS + pbase + tid] = b;
            pidx [half * NPTS + pbase + tid] = bi;
        }
        // loop-top __syncthreads protects xs/red reuse
    }
}

// ---------------- merge the two code-half candidates ----------------
__global__ void k_merge(const float* __restrict__ pbest, const int* __restrict__ pidx,
                        int* __restrict__ idxq) {
    int n = blockIdx.x * blockDim.x + threadIdx.x;   // NPTS
    float a = pbest[n], b = pbest[NPTS + n];
    int ia = pidx[n], ib = pidx[NPTS + n];
    idxq[n] = (b < a) ? ib : ia;        // tie -> half 0 (lower k): first-min
}

// ---------------- residual/quant update (fp32, exact np order) ----------------
__global__ void k_update(const float* __restrict__ cb, const int* __restrict__ idx,
                         float* __restrict__ resid, float* __restrict__ quant) {
    int gid = blockIdx.x * blockDim.x + threadIdx.x;   // NPTS*32
    int n = gid >> 5, d4 = (gid & 31) * 4;
    int k = idx[n];
    float4 c = *(const float4*)(cb + (size_t)k * D + d4);
    size_t o = (size_t)n * D + d4;
    float4 r = *(const float4*)(resid + o);
    float4 q = *(const float4*)(quant + o);
    r.x = __fsub_rn(r.x, c.x); r.y = __fsub_rn(r.y, c.y);
    r.z = __fsub_rn(r.z, c.z); r.w = __fsub_rn(r.w, c.w);
    q.x = __fadd_rn(q.x, c.x); q.y = __fadd_rn(q.y, c.y);
    q.z = __fadd_rn(q.z, c.z); q.w = __fadd_rn(q.w, c.w);
    *(float4*)(resid + o) = r;
    *(float4*)(quant + o) = q;
}

// ---------------- out0 = fl(z + fl(q - z)) transposed; commitment partial ----------------
__global__ __launch_bounds__(256) void k_out0(const float* __restrict__ z,
                                              const float* __restrict__ quant,
                                              float* __restrict__ out0,
                                              double* __restrict__ csum) {
    __shared__ float xt[64][129];
    __shared__ double wsum[4];
    int b = blockIdx.x >> 6, st = blockIdx.x & 63;
    int s0 = st * 64;
    for (int it = 0; it < 8; ++it) {
        int flat = it * 256 + threadIdx.x;
        int sl = flat >> 5, dq = (flat & 31) * 4;
        float4 q = *(const float4*)(quant + (size_t)(b * SLEN + s0 + sl) * D + dq);
        xt[sl][dq] = q.x; xt[sl][dq + 1] = q.y;
        xt[sl][dq + 2] = q.z; xt[sl][dq + 3] = q.w;
    }
    __syncthreads();
    double v = 0.0;
    for (int it = 0; it < 32; ++it) {
        int flat = it * 256 + threadIdx.x;
        int d = flat >> 6, sl = flat & 63;
        size_t o = ((size_t)(b * D + d)) * SLEN + s0 + sl;
        float zz = z[o], qq = xt[sl][d];
        out0[o] = __fadd_rn(zz, __fsub_rn(qq, zz));
        float e = __fsub_rn(zz, qq);
        v += (double)e * (double)e;
    }
    for (int off = 32; off > 0; off >>= 1) v += __shfl_down(v, off, 64);
    int lane = threadIdx.x & 63, wv = threadIdx.x >> 6;
    if (lane == 0) wsum[wv] = v;
    __syncthreads();
    if (threadIdx.x == 0) {
        double tsum = wsum[0] + wsum[1] + wsum[2] + wsum[3];
        atomicAdd(csum, tsum);
    }
}

// ---------------- indices output as float ----------------
__global__ void k_outidx(const int* __restrict__ idx, float* __restrict__ out1) {
    int o = blockIdx.x * blockDim.x + threadIdx.x;   // NPTS*NQ
    int q = o & 7, n = o >> 3;
    out1[o] = (float)idx[q * NPTS + n];
}

// ---------------- histogram ----------------
__global__ void k_hist(const int* __restrict__ idx, int* __restrict__ hist) {
    int o = blockIdx.x * blockDim.x + threadIdx.x;   // NQ*NPTS (layout [q][n])
    int q = o >> 15;
    atomicAdd(&hist[q * KCODES + idx[o]], 1);
}

// ---------------- final scalars ----------------
__global__ __launch_bounds__(256) void k_final(const int* __restrict__ hist,
                                               const double* __restrict__ csum,
                                               float* __restrict__ outs) {
    __shared__ double sh[256];
    double perp = 0.0;
    for (int q = 0; q < NQ; ++q) {
        double h = 0.0;
        for (int k = threadIdx.x; k < KCODES; k += 256) {
            double p = (double)hist[q * KCODES + k] / (double)NPTS;
            h -= p * log(p + 1e-10);
        }
        sh[threadIdx.x] = h; __syncthreads();
        for (int off = 128; off > 0; off >>= 1) {
            if (threadIdx.x < off) sh[threadIdx.x] += sh[threadIdx.x + off];
            __syncthreads();
        }
        if (threadIdx.x == 0) perp += exp(sh[0]);
        __syncthreads();
    }
    if (threadIdx.x == 0) {
        outs[0] = (float)(*csum / (double)((size_t)NPTS * D));
        outs[1] = (float)(perp / (double)NQ);
    }
}

extern "C" void kernel_launch(void* const* d_in, const int* in_sizes, int n_in,
                              void* d_out, int out_size, void* d_ws, size_t ws_size,
                              hipStream_t stream) {
    const float* z  = (const float*)d_in[0];
    const float* cb = (const float*)d_in[1];
    float* out0 = (float*)d_out;                 // 4,194,304 floats [B,D,S]
    float* out1 = out0 + 4194304;                // 262,144 floats  [B,S,Q]
    float* outs = out1 + 262144;                 // 2 scalars

    char* w = (char*)d_ws;
    float* resid  = (float*)w;                           // 16,777,216 B
    float* quant  = (float*)(w + 16777216);              // 16,777,216 B
    int*   idx    = (int*)(w + 33554432);                //  1,048,576 B
    int*   hist   = (int*)(w + 34603008);                //     32,768 B
    double* csum  = (double*)(w + 34635776);             //         64 B
    float* c2f    = (float*)(w + 34635840);              //     32,768 B
    float* pbest  = (float*)(w + 34668608);              //    262,144 B
    int*   pidx   = (int*)(w + 34930752);                //    262,144 B
    int*   ctr    = (int*)(w + 35192896);                //         32 B

    k_zero<<<32, 256, 0, stream>>>(hist, csum, ctr);
    k_c2<<<32, 256, 0, stream>>>(cb, c2f);
    k_init<<<512, 256, 0, stream>>>(z, resid, quant);

    for (int q = 0; q < NQ; ++q) {
        const float* cbq = cb + (size_t)q * KCODES * D;
        k_argmin<<<768, 256, 0, stream>>>(cbq, c2f + q * KCODES, resid,
                                          pbest, pidx, ctr + q);
        k_merge<<<NPTS / 256, 256, 0, stream>>>(pbest, pidx, idx + q * NPTS);
        k_update<<<NPTS * 32 / 256, 256, 0, stream>>>(cbq, idx + q * NPTS,
                                                      resid, quant);
    }

    k_out0<<<512, 256, 0, stream>>>(z, quant, out0, csum);
    k_outidx<<<NPTS * NQ / 256, 256, 0, stream>>>(idx, out1);
    k_hist<<<NPTS * NQ / 256, 256, 0, stream>>>(idx, hist);
    k_final<<<1, 256, 0, stream>>>(hist, csum, outs);
}

// Round 6
// 1177.324 us; speedup vs baseline: 12.3379x; 12.3379x over previous
//
#include <hip/hip_runtime.h>
#include <math.h>
#include <stdint.h>

#define D       128
#define KCODES  1024
#define NQ      8
#define BATCH   8
#define SLEN    4096
#define NPTS    (BATCH*SLEN)     /* 32768 */
#define TM      64               /* points per argmin block */

// async global->LDS, 16B per lane (wave-uniform LDS base + lane*16)
typedef __attribute__((address_space(1))) const void GV;
typedef __attribute__((address_space(3))) void LV;
__device__ __forceinline__ void gload16(const void* g, void* l) {
    __builtin_amdgcn_global_load_lds((GV*)g, (LV*)l, 16, 0, 0);
}

// ---------------- zero scratch ----------------
__global__ void k_zero(int* hist, double* csum) {
    int t = blockIdx.x * blockDim.x + threadIdx.x;
    if (t < NQ * KCODES) hist[t] = 0;
    if (t == 0) *csum = 0.0;
}

// ---------------- codebook norms: numpy pairwise fp32 ----------------
__global__ void k_c2(const float* __restrict__ cbs, float* __restrict__ c2f) {
    int i = blockIdx.x * blockDim.x + threadIdx.x;   // 0..8191
    const float* row = cbs + (size_t)i * D;
    float r8[8];
    #pragma unroll
    for (int j = 0; j < 8; ++j) r8[j] = __fmul_rn(row[j], row[j]);
    for (int d = 8; d < 128; d += 8)
        #pragma unroll
        for (int j = 0; j < 8; ++j)
            r8[j] = __fadd_rn(r8[j], __fmul_rn(row[d + j], row[d + j]));
    float s01 = __fadd_rn(r8[0], r8[1]);
    float s23 = __fadd_rn(r8[2], r8[3]);
    float s45 = __fadd_rn(r8[4], r8[5]);
    float s67 = __fadd_rn(r8[6], r8[7]);
    c2f[i] = __fadd_rn(__fadd_rn(s01, s23), __fadd_rn(s45, s67));
}

// ---------------- init: z [B,D,S] -> resid fp32 [n][d]; quant = 0 ----------------
__global__ __launch_bounds__(256) void k_init(const float* __restrict__ z,
                                              float* __restrict__ resid,
                                              float* __restrict__ quant) {
    __shared__ float xt[64][129];
    int b = blockIdx.x >> 6, st = blockIdx.x & 63;
    int s0 = st * 64;
    for (int it = 0; it < 32; ++it) {
        int flat = it * 256 + threadIdx.x;
        int d = flat >> 6, sl = flat & 63;
        xt[sl][d] = z[((size_t)(b * D + d)) * SLEN + s0 + sl];
    }
    __syncthreads();
    for (int it = 0; it < 8; ++it) {
        int flat = it * 256 + threadIdx.x;
        int sl = flat >> 5, dq = (flat & 31) * 4;
        size_t o = (size_t)(b * SLEN + s0 + sl) * D + dq;
        float4 r;
        r.x = xt[sl][dq]; r.y = xt[sl][dq + 1];
        r.z = xt[sl][dq + 2]; r.w = xt[sl][dq + 3];
        *(float4*)(resid + o) = r;
        float4 zz; zz.x = zz.y = zz.z = zz.w = 0.0f;
        *(float4*)(quant + o) = zz;
    }
}

// ---------------- fp32-emulated argmin (matches numpy/BLAS rounding) ----------------
// r6 = r3 structure (barrier-free, 4 waves, double-buffered DMA, 2 blocks/CU)
// with an 8pt x 16code per-thread tile: LDS ds_read traffic -25% per FLOP
// (the per-CU LDS pipe is the binding resource; FMA floor is per-SIMD).
// Wave w owns codes [256w,256w+256) in 2 chunks of 128. pl=l&7, cl=l>>3;
// code = w*256 + c*128 + cl + 8*jj (jj=0..15). K sliced 8 dims/step (32B
// rows in cs): cf reads hit 8 adjacent 32B rows = 64 words -> only 2-way
// bank aliasing, which is free -> NO swizzle needed, linear DMA source.
// cs double-buffered 2x4KB/wave; ISSUE(t+1) then vmcnt(4) (slice t home,
// t+1 in flight). No barriers in the main loop (cs is wave-private).
// Exact fp32 semantics (verified r2/r3): per (point,code) single FMA chain
// over dims 0..127 ascending; score fl(fl(xx-2*acc)+cc); first-min
// (strict <, candidates processed in ascending k; lex (score,k) reduce).
__global__ __launch_bounds__(256) void k_argmin(const float* __restrict__ cb,
                                                const float* __restrict__ c2,
                                                const float* __restrict__ resid,
                                                int* __restrict__ idx_out) {
    __shared__ __align__(16) float xs[TM][132];       // 33,792 B
    __shared__ float xxs[TM];                         //    256 B
    __shared__ __align__(16) float cs[4][2][128][8];  // 32,768 B/wave-dbuf
    __shared__ __align__(16) float ccl[4][256];       //  4,096 B per-wave c2
    __shared__ float redS[4][TM];                     //  1,024 B
    __shared__ int   redI[4][TM];                     //  1,024 B

    int tid = threadIdx.x;
    int pbase = blockIdx.x * TM;
    int l = tid & 63, w = tid >> 6;
    int pl = l & 7, cl = l >> 3;

    const char* cwb = (const char*)cb + ((size_t)w << 17);  // wave's 256 code rows
    // DMA per-lane source within a (chunk,slice,g) unit: row l>>1 (512B rows),
    // 16B half (l&1). Dest is linear: base + g*1024 + l*16 (row l>>1, half l&1).
    int gsrc_lane = ((l >> 1) << 9) + ((l & 1) << 4);
    char* csw = (char*)&cs[w][0][0][0];
    const char* xsb = (const char*)&xs[0][0];

    // prologue: slice 0 (chunk 0) DMA into buf 0
    {
        const char* src = cwb + gsrc_lane;
        gload16(src,             csw);
        gload16(src + (1 << 14), csw + 1024);
        gload16(src + (2 << 14), csw + 2048);
        gload16(src + (3 << 14), csw + 3072);
    }
    // c2 stage: wave's 256 values, one float4 per lane
    {
        float4 cv = *(const float4*)(c2 + (w << 8) + l * 4);
        *(float4*)&ccl[w][l * 4] = cv;
    }

    // stage X tile (fp32 residual), coalesced float4
    #pragma unroll
    for (int it = 0; it < 8; ++it) {
        int e = (it * 256 + tid) * 4;
        int p = e >> 7, d = e & 127;
        *(float4*)&xs[p][d] = *(const float4*)(resid + (size_t)(pbase + p) * D + d);
    }
    __syncthreads();

    // xx per point: numpy pairwise n=128 (8-accumulator pattern)
    if (tid < TM) {
        float r8[8];
        #pragma unroll
        for (int j = 0; j < 8; ++j) r8[j] = __fmul_rn(xs[tid][j], xs[tid][j]);
        for (int i = 8; i < 128; i += 8)
            #pragma unroll
            for (int j = 0; j < 8; ++j)
                r8[j] = __fadd_rn(r8[j], __fmul_rn(xs[tid][i + j], xs[tid][i + j]));
        float s01 = __fadd_rn(r8[0], r8[1]);
        float s23 = __fadd_rn(r8[2], r8[3]);
        float s45 = __fadd_rn(r8[4], r8[5]);
        float s67 = __fadd_rn(r8[6], r8[7]);
        xxs[tid] = __fadd_rn(__fadd_rn(s01, s23), __fadd_rn(s45, s67));
    }
    __syncthreads();

    float xxr[8];
    #pragma unroll
    for (int i = 0; i < 8; ++i) xxr[i] = xxs[pl + 8 * i];

    float acc[8][16];
    #pragma unroll
    for (int i = 0; i < 8; ++i)
        #pragma unroll
        for (int j = 0; j < 16; ++j) acc[i][j] = 0.0f;
    float best[8]; int bidx[8];
    #pragma unroll
    for (int i = 0; i < 8; ++i) { best[i] = 3.4e38f; bidx[i] = 0; }

    #pragma unroll 1
    for (int t = 0; t < 32; ++t) {           // t = chunk*16 + slice (8 dims each)
        int c = t >> 4, s = t & 15, buf = t & 1;
        if (t < 31) {                        // issue next slice into other buf
            int t2 = t + 1;
            const char* src = cwb + gsrc_lane + ((t2 >> 4) << 16) + ((t2 & 15) << 5);
            char* dst = csw + ((t2 & 1) << 12);
            gload16(src,             dst);
            gload16(src + (1 << 14), dst + 1024);
            gload16(src + (2 << 14), dst + 2048);
            gload16(src + (3 << 14), dst + 3072);
            asm volatile("s_waitcnt vmcnt(4)" ::: "memory");   // slice t arrived
        } else {
            asm volatile("s_waitcnt vmcnt(0)" ::: "memory");
        }
        // compute slice t from buf: 2 d4-steps x (8 xf + 16 cf reads, 512 FMA)
        const char* cbuf = csw + (buf << 12) + (cl << 5);  // row=cl base (32B rows)
        const char* xrow = xsb + pl * 528 + (s << 5);      // dims 8s..8s+7
        #pragma unroll
        for (int d4 = 0; d4 < 2; ++d4) {
            float4 xf[8];
            #pragma unroll
            for (int i = 0; i < 8; ++i)
                xf[i] = *(const float4*)(xrow + i * 4224 + (d4 << 4));
            #pragma unroll
            for (int jb = 0; jb < 4; ++jb) {
                float4 cf[4];
                #pragma unroll
                for (int j = 0; j < 4; ++j)
                    cf[j] = *(const float4*)(cbuf + ((jb * 4 + j) << 8) + (d4 << 4));
                #pragma unroll
                for (int j = 0; j < 4; ++j) {
                    int jj = jb * 4 + j;
                    #pragma unroll
                    for (int i = 0; i < 8; ++i) {
                        acc[i][jj] = __fmaf_rn(xf[i].x, cf[j].x, acc[i][jj]);
                        acc[i][jj] = __fmaf_rn(xf[i].y, cf[j].y, acc[i][jj]);
                        acc[i][jj] = __fmaf_rn(xf[i].z, cf[j].z, acc[i][jj]);
                        acc[i][jj] = __fmaf_rn(xf[i].w, cf[j].w, acc[i][jj]);
                    }
                }
            }
        }
        if (s == 15) {                       // end of 128-code chunk: fold scores
            #pragma unroll
            for (int j = 0; j < 16; ++j) {
                float cc = ccl[w][(c << 7) + cl + (j << 3)];
                int k = (w << 8) + (c << 7) + cl + (j << 3);
                #pragma unroll
                for (int i = 0; i < 8; ++i) {
                    float t1  = __fadd_rn(xxr[i], __fmul_rn(-2.0f, acc[i][j]));
                    float dsc = __fadd_rn(t1, cc);
                    if (dsc < best[i]) { best[i] = dsc; bidx[i] = k; }  // k ascending
                    acc[i][j] = 0.0f;
                }
            }
        }
    }

    // cross-lane (cl bits 3..5) lexicographic argmin reduce, then cross-wave
    #pragma unroll
    for (int i = 0; i < 8; ++i) {
        float b = best[i]; int bi = bidx[i];
        #pragma unroll
        for (int off = 8; off < 64; off <<= 1) {
            float b2 = __shfl_xor(b, off, 64);
            int  bi2 = __shfl_xor(bi, off, 64);
            if (b2 < b || (b2 == b && bi2 < bi)) { b = b2; bi = bi2; }
        }
        if (cl == 0) { redS[w][pl + 8 * i] = b; redI[w][pl + 8 * i] = bi; }
    }
    __syncthreads();
    if (tid < TM) {
        float b = redS[0][tid]; int bi = redI[0][tid];
        #pragma unroll
        for (int ww = 1; ww < 4; ++ww) {
            float b2 = redS[ww][tid]; int bi2 = redI[ww][tid];
            if (b2 < b || (b2 == b && bi2 < bi)) { b = b2; bi = bi2; }
        }
        idx_out[pbase + tid] = bi;
    }
}

// ---------------- residual/quant update (fp32, exact np order) ----------------
__global__ void k_update(const float* __restrict__ cb, const int* __restrict__ idx,
                         float* __restrict__ resid, float* __restrict__ quant) {
    int gid = blockIdx.x * blockDim.x + threadIdx.x;   // NPTS*32
    int n = gid >> 5, d4 = (gid & 31) * 4;
    int k = idx[n];
    float4 c = *(const float4*)(cb + (size_t)k * D + d4);
    size_t o = (size_t)n * D + d4;
    float4 r = *(const float4*)(resid + o);
    float4 q = *(const float4*)(quant + o);
    r.x = __fsub_rn(r.x, c.x); r.y = __fsub_rn(r.y, c.y);
    r.z = __fsub_rn(r.z, c.z); r.w = __fsub_rn(r.w, c.w);
    q.x = __fadd_rn(q.x, c.x); q.y = __fadd_rn(q.y, c.y);
    q.z = __fadd_rn(q.z, c.z); q.w = __fadd_rn(q.w, c.w);
    *(float4*)(resid + o) = r;
    *(float4*)(quant + o) = q;
}

// ---------------- out0 = fl(z + fl(q - z)) transposed; commitment partial ----------------
__global__ __launch_bounds__(256) void k_out0(const float* __restrict__ z,
                                              const float* __restrict__ quant,
                                              float* __restrict__ out0,
                                              double* __restrict__ csum) {
    __shared__ float xt[64][129];
    __shared__ double wsum[4];
    int b = blockIdx.x >> 6, st = blockIdx.x & 63;
    int s0 = st * 64;
    for (int it = 0; it < 8; ++it) {
        int flat = it * 256 + threadIdx.x;
        int sl = flat >> 5, dq = (flat & 31) * 4;
        float4 q = *(const float4*)(quant + (size_t)(b * SLEN + s0 + sl) * D + dq);
        xt[sl][dq] = q.x; xt[sl][dq + 1] = q.y;
        xt[sl][dq + 2] = q.z; xt[sl][dq + 3] = q.w;
    }
    __syncthreads();
    double v = 0.0;
    for (int it = 0; it < 32; ++it) {
        int flat = it * 256 + threadIdx.x;
        int d = flat >> 6, sl = flat & 63;
        size_t o = ((size_t)(b * D + d)) * SLEN + s0 + sl;
        float zz = z[o], qq = xt[sl][d];
        out0[o] = __fadd_rn(zz, __fsub_rn(qq, zz));
        float e = __fsub_rn(zz, qq);
        v += (double)e * (double)e;
    }
    for (int off = 32; off > 0; off >>= 1) v += __shfl_down(v, off, 64);
    int lane = threadIdx.x & 63, wv = threadIdx.x >> 6;
    if (lane == 0) wsum[wv] = v;
    __syncthreads();
    if (threadIdx.x == 0) {
        double tsum = wsum[0] + wsum[1] + wsum[2] + wsum[3];
        atomicAdd(csum, tsum);
    }
}

// ---------------- indices output as float ----------------
__global__ void k_outidx(const int* __restrict__ idx, float* __restrict__ out1) {
    int o = blockIdx.x * blockDim.x + threadIdx.x;   // NPTS*NQ
    int q = o & 7, n = o >> 3;
    out1[o] = (float)idx[q * NPTS + n];
}

// ---------------- histogram ----------------
__global__ void k_hist(const int* __restrict__ idx, int* __restrict__ hist) {
    int o = blockIdx.x * blockDim.x + threadIdx.x;   // NQ*NPTS (layout [q][n])
    int q = o >> 15;
    atomicAdd(&hist[q * KCODES + idx[o]], 1);
}

// ---------------- final scalars ----------------
__global__ __launch_bounds__(256) void k_final(const int* __restrict__ hist,
                                               const double* __restrict__ csum,
                                               float* __restrict__ outs) {
    __shared__ double sh[256];
    double perp = 0.0;
    for (int q = 0; q < NQ; ++q) {
        double h = 0.0;
        for (int k = threadIdx.x; k < KCODES; k += 256) {
            double p = (double)hist[q * KCODES + k] / (double)NPTS;
            h -= p * log(p + 1e-10);
        }
        sh[threadIdx.x] = h; __syncthreads();
        for (int off = 128; off > 0; off >>= 1) {
            if (threadIdx.x < off) sh[threadIdx.x] += sh[threadIdx.x + off];
            __syncthreads();
        }
        if (threadIdx.x == 0) perp += exp(sh[0]);
        __syncthreads();
    }
    if (threadIdx.x == 0) {
        outs[0] = (float)(*csum / (double)((size_t)NPTS * D));
        outs[1] = (float)(perp / (double)NQ);
    }
}

extern "C" void kernel_launch(void* const* d_in, const int* in_sizes, int n_in,
                              void* d_out, int out_size, void* d_ws, size_t ws_size,
                              hipStream_t stream) {
    const float* z  = (const float*)d_in[0];
    const float* cb = (const float*)d_in[1];
    float* out0 = (float*)d_out;                 // 4,194,304 floats [B,D,S]
    float* out1 = out0 + 4194304;                // 262,144 floats  [B,S,Q]
    float* outs = out1 + 262144;                 // 2 scalars

    char* w = (char*)d_ws;
    float* resid  = (float*)w;                           // 16,777,216 B
    float* quant  = (float*)(w + 16777216);              // 16,777,216 B
    int*   idx    = (int*)(w + 33554432);                //  1,048,576 B
    int*   hist   = (int*)(w + 34603008);                //     32,768 B
    double* csum  = (double*)(w + 34635776);             //         64 B
    float* c2f    = (float*)(w + 34635840);              //     32,768 B

    k_zero<<<32, 256, 0, stream>>>(hist, csum);
    k_c2<<<32, 256, 0, stream>>>(cb, c2f);
    k_init<<<512, 256, 0, stream>>>(z, resid, quant);

    for (int q = 0; q < NQ; ++q) {
        const float* cbq = cb + (size_t)q * KCODES * D;
        k_argmin<<<NPTS / TM, 256, 0, stream>>>(cbq, c2f + q * KCODES, resid,
                                                idx + q * NPTS);
        k_update<<<NPTS * 32 / 256, 256, 0, stream>>>(cbq, idx + q * NPTS,
                                                      resid, quant);
    }

    k_out0<<<512, 256, 0, stream>>>(z, quant, out0, csum);
    k_outidx<<<NPTS * NQ / 256, 256, 0, stream>>>(idx, out1);
    k_hist<<<NPTS * NQ / 256, 256, 0, stream>>>(idx, hist);
    k_final<<<1, 256, 0, stream>>>(hist, csum, outs);
}

// Round 7
// 1168.422 us; speedup vs baseline: 12.4319x; 1.0076x over previous
//
#include <hip/hip_runtime.h>
#include <math.h>
#include <stdint.h>

#define D       128
#define KCODES  1024
#define NQ      8
#define BATCH   8
#define SLEN    4096
#define NPTS    (BATCH*SLEN)     /* 32768 */
#define TM      64               /* points per argmin unit */

// async global->LDS, 16B per lane (wave-uniform LDS base + lane*16)
typedef __attribute__((address_space(1))) const void GV;
typedef __attribute__((address_space(3))) void LV;
__device__ __forceinline__ void gload16(const void* g, void* l) {
    __builtin_amdgcn_global_load_lds((GV*)g, (LV*)l, 16, 0, 0);
}

// ---------------- zero scratch ----------------
__global__ void k_zero(int* hist, double* csum) {
    int t = blockIdx.x * blockDim.x + threadIdx.x;
    if (t < NQ * KCODES) hist[t] = 0;
    if (t == 0) *csum = 0.0;
}

// ---------------- codebook norms: numpy pairwise fp32 ----------------
__global__ void k_c2(const float* __restrict__ cbs, float* __restrict__ c2f) {
    int i = blockIdx.x * blockDim.x + threadIdx.x;   // 0..8191
    const float* row = cbs + (size_t)i * D;
    float r8[8];
    #pragma unroll
    for (int j = 0; j < 8; ++j) r8[j] = __fmul_rn(row[j], row[j]);
    for (int d = 8; d < 128; d += 8)
        #pragma unroll
        for (int j = 0; j < 8; ++j)
            r8[j] = __fadd_rn(r8[j], __fmul_rn(row[d + j], row[d + j]));
    float s01 = __fadd_rn(r8[0], r8[1]);
    float s23 = __fadd_rn(r8[2], r8[3]);
    float s45 = __fadd_rn(r8[4], r8[5]);
    float s67 = __fadd_rn(r8[6], r8[7]);
    c2f[i] = __fadd_rn(__fadd_rn(s01, s23), __fadd_rn(s45, s67));
}

// ---------------- init: z [B,D,S] -> resid fp32 [n][d]; quant = 0 ----------------
__global__ __launch_bounds__(256) void k_init(const float* __restrict__ z,
                                              float* __restrict__ resid,
                                              float* __restrict__ quant) {
    __shared__ float xt[64][129];
    int b = blockIdx.x >> 6, st = blockIdx.x & 63;
    int s0 = st * 64;
    for (int it = 0; it < 32; ++it) {
        int flat = it * 256 + threadIdx.x;
        int d = flat >> 6, sl = flat & 63;
        xt[sl][d] = z[((size_t)(b * D + d)) * SLEN + s0 + sl];
    }
    __syncthreads();
    for (int it = 0; it < 8; ++it) {
        int flat = it * 256 + threadIdx.x;
        int sl = flat >> 5, dq = (flat & 31) * 4;
        size_t o = (size_t)(b * SLEN + s0 + sl) * D + dq;
        float4 r;
        r.x = xt[sl][dq]; r.y = xt[sl][dq + 1];
        r.z = xt[sl][dq + 2]; r.w = xt[sl][dq + 3];
        *(float4*)(resid + o) = r;
        float4 zz; zz.x = zz.y = zz.z = zz.w = 0.0f;
        *(float4*)(quant + o) = zz;
    }
}

// ---------------- fp32-emulated argmin (matches numpy/BLAS rounding) ----------------
// r7: 3 blocks/CU (12 waves/CU) occupancy push, NO launch_bounds min-arg
// (r1/r5 lesson: its VGPR cap is computed wave32-style = 512/2N -> spills).
// Grid 1024 = 512 point-blocks x 2 code-halves (r5-verified split+merge).
// Per unit: 64 pts x 512 codes; wave w owns the 128 codes
// [half*512 + w*128, +128) -- exactly one fold chunk. pl=l&7, cl=l>>3;
// per-thread tile 8 pts x 16 codes (acc[8][16], VGPR ~136 measured r6).
// K sliced 4 dims/slice; cs[wave][2][128 codes x 4dims] 16B rows,
// double-buffered, linear DMA source (row l), vmcnt(2) gate (slice t
// arrived, t+1 in flight). cf reads: 8 rows cl -> banks 4cl..4cl+3,
// conflict-free; broadcast over pl (r6-verified 0 conflicts).
// LDS total 54,272 B (+256 runtime) -> 3 blocks/CU; xx lives in xs pad
// col 128 (r5-verified); redS/redI separate arrays (r4 race lesson).
// Exact fp32 semantics (r2/r3/r6-verified): per (point,code) single FMA
// chain dims 0..127 ascending; score fl(fl(xx-2*acc)+cc); first-min
// (strict <, k ascending; lex (score,k) reduce; merge tie -> lower half).
__global__ __launch_bounds__(256) void k_argmin(const float* __restrict__ cb,
                                                const float* __restrict__ c2,
                                                const float* __restrict__ resid,
                                                float* __restrict__ pbest,
                                                int* __restrict__ pidx) {
    __shared__ __align__(16) float xs[TM][132];       // 33,792 B (xx in col 128)
    __shared__ __align__(16) float cs[4][2][512];     // 16,384 B: [wave][buf][128c x 4d]
    __shared__ __align__(16) float ccl[4][128];       //  2,048 B: per-wave c2
    __shared__ float redS[4][TM];                     //  1,024 B
    __shared__ int   redI[4][TM];                     //  1,024 B

    int tid = threadIdx.x;
    int u = blockIdx.x;
    int pblk = u >> 1, half = u & 1;
    int pbase = pblk * TM;
    int l = tid & 63, w = tid >> 6;
    int pl = l & 7, cl = l >> 3;

    // wave's 128 code rows (512 B each)
    const char* cwb = (const char*)cb + ((size_t)(half * 512 + w * 128) << 9);
    char* csw = (char*)&cs[w][0][0];
    const char* xsb = (const char*)&xs[0][0];

    // ISSUE(slice s): 2 async loads; lane l covers rows l and 64+l; the 16B
    // at byte s*16 of each row lands at dst + lane*16 (linear).
#define ISSUE(S) { \
    const char* _src = cwb + ((size_t)l << 9) + ((S) << 4); \
    char* _dst = csw + (((S) & 1) << 11); \
    gload16(_src,             _dst); \
    gload16(_src + (1 << 15), _dst + 1024); }

    // prologue: slice 0 into buf 0
    ISSUE(0);
    // c2 stage: wave's 128 values (lanes 0..31, one float4 each)
    if (l < 32) {
        float4 cv = *(const float4*)(c2 + half * 512 + w * 128 + l * 4);
        *(float4*)&ccl[w][l * 4] = cv;
    }

    // stage X tile (fp32 residual), coalesced float4
    #pragma unroll
    for (int it = 0; it < 8; ++it) {
        int e = (it * 256 + tid) * 4;
        int p = e >> 7, d = e & 127;
        *(float4*)&xs[p][d] = *(const float4*)(resid + (size_t)(pbase + p) * D + d);
    }
    __syncthreads();

    // xx per point: numpy pairwise n=128 (8-accumulator pattern); store in pad
    if (tid < TM) {
        float r8[8];
        #pragma unroll
        for (int j = 0; j < 8; ++j) r8[j] = __fmul_rn(xs[tid][j], xs[tid][j]);
        for (int i = 8; i < 128; i += 8)
            #pragma unroll
            for (int j = 0; j < 8; ++j)
                r8[j] = __fadd_rn(r8[j], __fmul_rn(xs[tid][i + j], xs[tid][i + j]));
        float s01 = __fadd_rn(r8[0], r8[1]);
        float s23 = __fadd_rn(r8[2], r8[3]);
        float s45 = __fadd_rn(r8[4], r8[5]);
        float s67 = __fadd_rn(r8[6], r8[7]);
        xs[tid][128] = __fadd_rn(__fadd_rn(s01, s23), __fadd_rn(s45, s67));
    }
    __syncthreads();

    float xxr[8];
    #pragma unroll
    for (int i = 0; i < 8; ++i) xxr[i] = xs[pl + 8 * i][128];

    float acc[8][16];
    #pragma unroll
    for (int i = 0; i < 8; ++i)
        #pragma unroll
        for (int j = 0; j < 16; ++j) acc[i][j] = 0.0f;
    float best[8]; int bidx[8];
    #pragma unroll
    for (int i = 0; i < 8; ++i) { best[i] = 3.4e38f; bidx[i] = 0; }

    #pragma unroll 1
    for (int t = 0; t < 32; ++t) {           // slice t = dims 4t..4t+3
        if (t < 31) {
            ISSUE(t + 1);
            asm volatile("s_waitcnt vmcnt(2)" ::: "memory");   // slice t arrived
        } else {
            asm volatile("s_waitcnt vmcnt(0)" ::: "memory");
        }
        const char* cbuf = csw + ((t & 1) << 11) + (cl << 4);  // row cl (16B rows)
        const char* xrow = xsb + pl * 528 + (t << 4);          // dims 4t..4t+3
        float4 xf[8];
        #pragma unroll
        for (int i = 0; i < 8; ++i)
            xf[i] = *(const float4*)(xrow + i * 4224);
        #pragma unroll
        for (int jb = 0; jb < 4; ++jb) {
            float4 cf[4];
            #pragma unroll
            for (int j = 0; j < 4; ++j)
                cf[j] = *(const float4*)(cbuf + ((jb * 4 + j) << 7)); // row cl+8jj
            #pragma unroll
            for (int j = 0; j < 4; ++j) {
                int jj = jb * 4 + j;
                #pragma unroll
                for (int i = 0; i < 8; ++i) {
                    acc[i][jj] = __fmaf_rn(xf[i].x, cf[j].x, acc[i][jj]);
                    acc[i][jj] = __fmaf_rn(xf[i].y, cf[j].y, acc[i][jj]);
                    acc[i][jj] = __fmaf_rn(xf[i].z, cf[j].z, acc[i][jj]);
                    acc[i][jj] = __fmaf_rn(xf[i].w, cf[j].w, acc[i][jj]);
                }
            }
        }
    }

    // fold scores (single 128-code chunk per wave)
    #pragma unroll
    for (int j = 0; j < 16; ++j) {
        float cc = ccl[w][cl + (j << 3)];
        int k = half * 512 + (w << 7) + cl + (j << 3);
        #pragma unroll
        for (int i = 0; i < 8; ++i) {
            float t1  = __fadd_rn(xxr[i], __fmul_rn(-2.0f, acc[i][j]));
            float dsc = __fadd_rn(t1, cc);
            if (dsc < best[i]) { best[i] = dsc; bidx[i] = k; }  // k ascending
        }
    }

    // cross-lane (cl bits 3..5) lexicographic argmin reduce, then cross-wave
    #pragma unroll
    for (int i = 0; i < 8; ++i) {
        float b = best[i]; int bi = bidx[i];
        #pragma unroll
        for (int off = 8; off < 64; off <<= 1) {
            float b2 = __shfl_xor(b, off, 64);
            int  bi2 = __shfl_xor(bi, off, 64);
            if (b2 < b || (b2 == b && bi2 < bi)) { b = b2; bi = bi2; }
        }
        if (cl == 0) { redS[w][pl + 8 * i] = b; redI[w][pl + 8 * i] = bi; }
    }
    __syncthreads();
    if (tid < TM) {
        float b = redS[0][tid]; int bi = redI[0][tid];
        #pragma unroll
        for (int ww = 1; ww < 4; ++ww) {
            float b2 = redS[ww][tid]; int bi2 = redI[ww][tid];
            if (b2 < b || (b2 == b && bi2 < bi)) { b = b2; bi = bi2; }
        }
        pbest[half * NPTS + pbase + tid] = b;
        pidx [half * NPTS + pbase + tid] = bi;
    }
#undef ISSUE
}

// ---------------- merge the two code-half candidates ----------------
__global__ void k_merge(const float* __restrict__ pbest, const int* __restrict__ pidx,
                        int* __restrict__ idxq) {
    int n = blockIdx.x * blockDim.x + threadIdx.x;   // NPTS
    float a = pbest[n], b = pbest[NPTS + n];
    int ia = pidx[n], ib = pidx[NPTS + n];
    idxq[n] = (b < a) ? ib : ia;        // tie -> half 0 (lower k): first-min
}

// ---------------- residual/quant update (fp32, exact np order) ----------------
__global__ void k_update(const float* __restrict__ cb, const int* __restrict__ idx,
                         float* __restrict__ resid, float* __restrict__ quant) {
    int gid = blockIdx.x * blockDim.x + threadIdx.x;   // NPTS*32
    int n = gid >> 5, d4 = (gid & 31) * 4;
    int k = idx[n];
    float4 c = *(const float4*)(cb + (size_t)k * D + d4);
    size_t o = (size_t)n * D + d4;
    float4 r = *(const float4*)(resid + o);
    float4 q = *(const float4*)(quant + o);
    r.x = __fsub_rn(r.x, c.x); r.y = __fsub_rn(r.y, c.y);
    r.z = __fsub_rn(r.z, c.z); r.w = __fsub_rn(r.w, c.w);
    q.x = __fadd_rn(q.x, c.x); q.y = __fadd_rn(q.y, c.y);
    q.z = __fadd_rn(q.z, c.z); q.w = __fadd_rn(q.w, c.w);
    *(float4*)(resid + o) = r;
    *(float4*)(quant + o) = q;
}

// ---------------- out0 = fl(z + fl(q - z)) transposed; commitment partial ----------------
__global__ __launch_bounds__(256) void k_out0(const float* __restrict__ z,
                                              const float* __restrict__ quant,
                                              float* __restrict__ out0,
                                              double* __restrict__ csum) {
    __shared__ float xt[64][129];
    __shared__ double wsum[4];
    int b = blockIdx.x >> 6, st = blockIdx.x & 63;
    int s0 = st * 64;
    for (int it = 0; it < 8; ++it) {
        int flat = it * 256 + threadIdx.x;
        int sl = flat >> 5, dq = (flat & 31) * 4;
        float4 q = *(const float4*)(quant + (size_t)(b * SLEN + s0 + sl) * D + dq);
        xt[sl][dq] = q.x; xt[sl][dq + 1] = q.y;
        xt[sl][dq + 2] = q.z; xt[sl][dq + 3] = q.w;
    }
    __syncthreads();
    double v = 0.0;
    for (int it = 0; it < 32; ++it) {
        int flat = it * 256 + threadIdx.x;
        int d = flat >> 6, sl = flat & 63;
        size_t o = ((size_t)(b * D + d)) * SLEN + s0 + sl;
        float zz = z[o], qq = xt[sl][d];
        out0[o] = __fadd_rn(zz, __fsub_rn(qq, zz));
        float e = __fsub_rn(zz, qq);
        v += (double)e * (double)e;
    }
    for (int off = 32; off > 0; off >>= 1) v += __shfl_down(v, off, 64);
    int lane = threadIdx.x & 63, wv = threadIdx.x >> 6;
    if (lane == 0) wsum[wv] = v;
    __syncthreads();
    if (threadIdx.x == 0) {
        double tsum = wsum[0] + wsum[1] + wsum[2] + wsum[3];
        atomicAdd(csum, tsum);
    }
}

// ---------------- indices output as float ----------------
__global__ void k_outidx(const int* __restrict__ idx, float* __restrict__ out1) {
    int o = blockIdx.x * blockDim.x + threadIdx.x;   // NPTS*NQ
    int q = o & 7, n = o >> 3;
    out1[o] = (float)idx[q * NPTS + n];
}

// ---------------- histogram ----------------
__global__ void k_hist(const int* __restrict__ idx, int* __restrict__ hist) {
    int o = blockIdx.x * blockDim.x + threadIdx.x;   // NQ*NPTS (layout [q][n])
    int q = o >> 15;
    atomicAdd(&hist[q * KCODES + idx[o]], 1);
}

// ---------------- final scalars ----------------
__global__ __launch_bounds__(256) void k_final(const int* __restrict__ hist,
                                               const double* __restrict__ csum,
                                               float* __restrict__ outs) {
    __shared__ double sh[256];
    double perp = 0.0;
    for (int q = 0; q < NQ; ++q) {
        double h = 0.0;
        for (int k = threadIdx.x; k < KCODES; k += 256) {
            double p = (double)hist[q * KCODES + k] / (double)NPTS;
            h -= p * log(p + 1e-10);
        }
        sh[threadIdx.x] = h; __syncthreads();
        for (int off = 128; off > 0; off >>= 1) {
            if (threadIdx.x < off) sh[threadIdx.x] += sh[threadIdx.x + off];
            __syncthreads();
        }
        if (threadIdx.x == 0) perp += exp(sh[0]);
        __syncthreads();
    }
    if (threadIdx.x == 0) {
        outs[0] = (float)(*csum / (double)((size_t)NPTS * D));
        outs[1] = (float)(perp / (double)NQ);
    }
}

extern "C" void kernel_launch(void* const* d_in, const int* in_sizes, int n_in,
                              void* d_out, int out_size, void* d_ws, size_t ws_size,
                              hipStream_t stream) {
    const float* z  = (const float*)d_in[0];
    const float* cb = (const float*)d_in[1];
    float* out0 = (float*)d_out;                 // 4,194,304 floats [B,D,S]
    float* out1 = out0 + 4194304;                // 262,144 floats  [B,S,Q]
    float* outs = out1 + 262144;                 // 2 scalars

    char* w = (char*)d_ws;
    float* resid  = (float*)w;                           // 16,777,216 B
    float* quant  = (float*)(w + 16777216);              // 16,777,216 B
    int*   idx    = (int*)(w + 33554432);                //  1,048,576 B
    int*   hist   = (int*)(w + 34603008);                //     32,768 B
    double* csum  = (double*)(w + 34635776);             //         64 B
    float* c2f    = (float*)(w + 34635840);              //     32,768 B
    float* pbest  = (float*)(w + 34668608);              //    262,144 B
    int*   pidx   = (int*)(w + 34930752);                //    262,144 B

    k_zero<<<32, 256, 0, stream>>>(hist, csum);
    k_c2<<<32, 256, 0, stream>>>(cb, c2f);
    k_init<<<512, 256, 0, stream>>>(z, resid, quant);

    for (int q = 0; q < NQ; ++q) {
        const float* cbq = cb + (size_t)q * KCODES * D;
        k_argmin<<<2 * NPTS / TM, 256, 0, stream>>>(cbq, c2f + q * KCODES, resid,
                                                    pbest, pidx);
        k_merge<<<NPTS / 256, 256, 0, stream>>>(pbest, pidx, idx + q * NPTS);
        k_update<<<NPTS * 32 / 256, 256, 0, stream>>>(cbq, idx + q * NPTS,
                                                      resid, quant);
    }

    k_out0<<<512, 256, 0, stream>>>(z, quant, out0, csum);
    k_outidx<<<NPTS * NQ / 256, 256, 0, stream>>>(idx, out1);
    k_hist<<<NPTS * NQ / 256, 256, 0, stream>>>(idx, hist);
    k_final<<<1, 256, 0, stream>>>(hist, csum, outs);
}

// Round 8
// 1166.569 us; speedup vs baseline: 12.4517x; 1.0016x over previous
//
#include <hip/hip_runtime.h>
#include <math.h>
#include <stdint.h>

#define D       128
#define KCODES  1024
#define NQ      8
#define BATCH   8
#define SLEN    4096
#define NPTS    (BATCH*SLEN)     /* 32768 */
#define TM      64               /* points per argmin unit */

// async global->LDS, 16B per lane (wave-uniform LDS base + lane*16)
typedef __attribute__((address_space(1))) const void GV;
typedef __attribute__((address_space(3))) void LV;
__device__ __forceinline__ void gload16(const void* g, void* l) {
    __builtin_amdgcn_global_load_lds((GV*)g, (LV*)l, 16, 0, 0);
}

// ---------------- zero scratch ----------------
__global__ void k_zero(int* hist, double* csum) {
    int t = blockIdx.x * blockDim.x + threadIdx.x;
    if (t < NQ * KCODES) hist[t] = 0;
    if (t == 0) *csum = 0.0;
}

// ---------------- codebook norms: numpy pairwise fp32 ----------------
__global__ void k_c2(const float* __restrict__ cbs, float* __restrict__ c2f) {
    int i = blockIdx.x * blockDim.x + threadIdx.x;   // 0..8191
    const float* row = cbs + (size_t)i * D;
    float r8[8];
    #pragma unroll
    for (int j = 0; j < 8; ++j) r8[j] = __fmul_rn(row[j], row[j]);
    for (int d = 8; d < 128; d += 8)
        #pragma unroll
        for (int j = 0; j < 8; ++j)
            r8[j] = __fadd_rn(r8[j], __fmul_rn(row[d + j], row[d + j]));
    float s01 = __fadd_rn(r8[0], r8[1]);
    float s23 = __fadd_rn(r8[2], r8[3]);
    float s45 = __fadd_rn(r8[4], r8[5]);
    float s67 = __fadd_rn(r8[6], r8[7]);
    c2f[i] = __fadd_rn(__fadd_rn(s01, s23), __fadd_rn(s45, s67));
}

// ---------------- init: z [B,D,S] -> resid fp32 [n][d]; quant = 0 ----------------
__global__ __launch_bounds__(256) void k_init(const float* __restrict__ z,
                                              float* __restrict__ resid,
                                              float* __restrict__ quant) {
    __shared__ float xt[64][129];
    int b = blockIdx.x >> 6, st = blockIdx.x & 63;
    int s0 = st * 64;
    for (int it = 0; it < 32; ++it) {
        int flat = it * 256 + threadIdx.x;
        int d = flat >> 6, sl = flat & 63;
        xt[sl][d] = z[((size_t)(b * D + d)) * SLEN + s0 + sl];
    }
    __syncthreads();
    for (int it = 0; it < 8; ++it) {
        int flat = it * 256 + threadIdx.x;
        int sl = flat >> 5, dq = (flat & 31) * 4;
        size_t o = (size_t)(b * SLEN + s0 + sl) * D + dq;
        float4 r;
        r.x = xt[sl][dq]; r.y = xt[sl][dq + 1];
        r.z = xt[sl][dq + 2]; r.w = xt[sl][dq + 3];
        *(float4*)(resid + o) = r;
        float4 zz; zz.x = zz.y = zz.z = zz.w = 0.0f;
        *(float4*)(quant + o) = zz;
    }
}

// ---------------- fp32-emulated argmin (matches numpy/BLAS rounding) ----------------
// r8: r7's 3-blocks/CU recipe (arch-VGPR<=128, LDS<=54KB, grid 1024) with
// an 8pt x 8code tile so the HOT register set (acc 64 + xf 32 + cf 8 +
// addr ~12 ~= 116) fits the 128-VGPR cap -> no AGPR copy tax on the FMAs
// (r7: VGPR=104 with 128 accs => per-FMA accvgpr copies; VALU busy 101us
// vs 55us floor). __launch_bounds__(256,2) pins the cap at 128 (r1-measured
// quirk: cap = 512/2N); cold values (xxr/best/bidx ~24) spill to AGPR with
// copies only at the 2 folds.
// Grid 1024 = 512 point-blocks x 2 code-halves (r5/r7-verified split;
// merge fused into k_update). Wave w owns the 128 codes
// [half*512+w*128, +128) in 2 chunks of 64. pl=l&7, cl=l>>3.
// K sliced 4 dims/slice; cs[wave][2buf][64 codes x 4 dims] 16B rows;
// ONE gload16 per slice (lane l -> code row l of chunk), vmcnt(1) gate.
// cf reads: 8 broadcast rows spread over all 32 banks, conflict-free
// (r7-verified geometry). LDS 46,080 B -> 3 blocks/CU.
// Exact fp32 semantics (r2..r7-verified): per (point,code) single FMA
// chain dims 0..127 ascending (one chunk per code, slices ascending);
// score fl(fl(xx-2*acc)+cc); first-min (strict <, k ascending; lex
// (score,k) reduce; cross-half merge tie -> lower half).
__global__ __launch_bounds__(256, 2) void k_argmin(const float* __restrict__ cb,
                                                   const float* __restrict__ c2,
                                                   const float* __restrict__ resid,
                                                   float* __restrict__ pbest,
                                                   int* __restrict__ pidx) {
    __shared__ __align__(16) float xs[TM][132];       // 33,792 B (xx in col 128)
    __shared__ __align__(16) float cs[4][2][256];     //  8,192 B: [wave][buf][64c x 4d]
    __shared__ __align__(16) float ccl[4][128];       //  2,048 B: per-wave c2
    __shared__ float redS[4][TM];                     //  1,024 B
    __shared__ int   redI[4][TM];                     //  1,024 B

    int tid = threadIdx.x;
    int u = blockIdx.x;
    int pblk = u >> 1, half = u & 1;
    int pbase = pblk * TM;
    int l = tid & 63, w = tid >> 6;
    int pl = l & 7, cl = l >> 3;

    // wave's 128 code rows (512 B each)
    const char* cwb = (const char*)cb + ((size_t)(half * 512 + w * 128) << 9);
    char* csw = (char*)&cs[w][0][0];
    const char* xsb = (const char*)&xs[0][0];

    // ISSUE(slice T): one async load; lane l covers code row (T>>5)*64+l,
    // bytes [(T&31)*16, +16). Dest linear: base + lane*16.
#define ISSUE(T) { \
    const char* _src = cwb + (((T) >> 5) << 15) + ((size_t)l << 9) + (((T) & 31) << 4); \
    gload16(_src, csw + (((T) & 1) << 10)); }

    // prologue: slice 0 into buf 0
    ISSUE(0);
    // c2 stage: wave's 128 values (lanes 0..31, one float4 each)
    if (l < 32) {
        float4 cv = *(const float4*)(c2 + half * 512 + w * 128 + l * 4);
        *(float4*)&ccl[w][l * 4] = cv;
    }

    // stage X tile (fp32 residual), coalesced float4
    #pragma unroll
    for (int it = 0; it < 8; ++it) {
        int e = (it * 256 + tid) * 4;
        int p = e >> 7, d = e & 127;
        *(float4*)&xs[p][d] = *(const float4*)(resid + (size_t)(pbase + p) * D + d);
    }
    __syncthreads();

    // xx per point: numpy pairwise n=128 (8-accumulator pattern); store in pad
    if (tid < TM) {
        float r8[8];
        #pragma unroll
        for (int j = 0; j < 8; ++j) r8[j] = __fmul_rn(xs[tid][j], xs[tid][j]);
        for (int i = 8; i < 128; i += 8)
            #pragma unroll
            for (int j = 0; j < 8; ++j)
                r8[j] = __fadd_rn(r8[j], __fmul_rn(xs[tid][i + j], xs[tid][i + j]));
        float s01 = __fadd_rn(r8[0], r8[1]);
        float s23 = __fadd_rn(r8[2], r8[3]);
        float s45 = __fadd_rn(r8[4], r8[5]);
        float s67 = __fadd_rn(r8[6], r8[7]);
        xs[tid][128] = __fadd_rn(__fadd_rn(s01, s23), __fadd_rn(s45, s67));
    }
    __syncthreads();

    float xxr[8];
    #pragma unroll
    for (int i = 0; i < 8; ++i) xxr[i] = xs[pl + 8 * i][128];

    float acc[8][8];
    #pragma unroll
    for (int i = 0; i < 8; ++i)
        #pragma unroll
        for (int j = 0; j < 8; ++j) acc[i][j] = 0.0f;
    float best[8]; int bidx[8];
    #pragma unroll
    for (int i = 0; i < 8; ++i) { best[i] = 3.4e38f; bidx[i] = 0; }

    #pragma unroll 1
    for (int t = 0; t < 64; ++t) {           // t = chunk*32 + slice(4 dims)
        if (t < 63) {
            ISSUE(t + 1);
            asm volatile("s_waitcnt vmcnt(1)" ::: "memory");   // slice t arrived
        } else {
            asm volatile("s_waitcnt vmcnt(0)" ::: "memory");
        }
        const char* cbuf = csw + ((t & 1) << 10) + (cl << 4);  // row cl (16B rows)
        const char* xrow = xsb + pl * 528 + ((t & 31) << 4);   // dims 4s..4s+3
        float4 xf[8];
        #pragma unroll
        for (int i = 0; i < 8; ++i)
            xf[i] = *(const float4*)(xrow + i * 4224);
        #pragma unroll
        for (int jp = 0; jp < 4; ++jp) {     // codes in pairs: low cf pressure
            float4 cf0 = *(const float4*)(cbuf + ((2 * jp)     << 7));
            float4 cf1 = *(const float4*)(cbuf + ((2 * jp + 1) << 7));
            #pragma unroll
            for (int i = 0; i < 8; ++i) {
                acc[i][2*jp]   = __fmaf_rn(xf[i].x, cf0.x, acc[i][2*jp]);
                acc[i][2*jp]   = __fmaf_rn(xf[i].y, cf0.y, acc[i][2*jp]);
                acc[i][2*jp]   = __fmaf_rn(xf[i].z, cf0.z, acc[i][2*jp]);
                acc[i][2*jp]   = __fmaf_rn(xf[i].w, cf0.w, acc[i][2*jp]);
                acc[i][2*jp+1] = __fmaf_rn(xf[i].x, cf1.x, acc[i][2*jp+1]);
                acc[i][2*jp+1] = __fmaf_rn(xf[i].y, cf1.y, acc[i][2*jp+1]);
                acc[i][2*jp+1] = __fmaf_rn(xf[i].z, cf1.z, acc[i][2*jp+1]);
                acc[i][2*jp+1] = __fmaf_rn(xf[i].w, cf1.w, acc[i][2*jp+1]);
            }
        }
        if ((t & 31) == 31) {                // end of 64-code chunk: fold
            int c = t >> 5;
            #pragma unroll
            for (int j = 0; j < 8; ++j) {
                float cc = ccl[w][(c << 6) + cl + (j << 3)];
                int k = half * 512 + (w << 7) + (c << 6) + cl + (j << 3);
                #pragma unroll
                for (int i = 0; i < 8; ++i) {
                    float t1  = __fadd_rn(xxr[i], __fmul_rn(-2.0f, acc[i][j]));
                    float dsc = __fadd_rn(t1, cc);
                    if (dsc < best[i]) { best[i] = dsc; bidx[i] = k; }  // k asc
                    acc[i][j] = 0.0f;
                }
            }
        }
    }

    // cross-lane (cl bits 3..5) lexicographic argmin reduce, then cross-wave
    #pragma unroll
    for (int i = 0; i < 8; ++i) {
        float b = best[i]; int bi = bidx[i];
        #pragma unroll
        for (int off = 8; off < 64; off <<= 1) {
            float b2 = __shfl_xor(b, off, 64);
            int  bi2 = __shfl_xor(bi, off, 64);
            if (b2 < b || (b2 == b && bi2 < bi)) { b = b2; bi = bi2; }
        }
        if (cl == 0) { redS[w][pl + 8 * i] = b; redI[w][pl + 8 * i] = bi; }
    }
    __syncthreads();
    if (tid < TM) {
        float b = redS[0][tid]; int bi = redI[0][tid];
        #pragma unroll
        for (int ww = 1; ww < 4; ++ww) {
            float b2 = redS[ww][tid]; int bi2 = redI[ww][tid];
            if (b2 < b || (b2 == b && bi2 < bi)) { b = b2; bi = bi2; }
        }
        pbest[half * NPTS + pbase + tid] = b;
        pidx [half * NPTS + pbase + tid] = bi;
    }
#undef ISSUE
}

// ---------------- fused merge + residual/quant update (fp32, exact np order) ----
__global__ void k_update(const float* __restrict__ cb,
                         const float* __restrict__ pbest,
                         const int* __restrict__ pidx,
                         int* __restrict__ idx,
                         float* __restrict__ resid, float* __restrict__ quant) {
    int gid = blockIdx.x * blockDim.x + threadIdx.x;   // NPTS*32
    int n = gid >> 5, d4 = (gid & 31) * 4;
    float a = pbest[n], b = pbest[NPTS + n];
    int ia = pidx[n], ib = pidx[NPTS + n];
    int k = (b < a) ? ib : ia;          // tie -> half 0 (lower k): first-min
    if ((gid & 31) == 0) idx[n] = k;
    float4 c = *(const float4*)(cb + (size_t)k * D + d4);
    size_t o = (size_t)n * D + d4;
    float4 r = *(const float4*)(resid + o);
    float4 q = *(const float4*)(quant + o);
    r.x = __fsub_rn(r.x, c.x); r.y = __fsub_rn(r.y, c.y);
    r.z = __fsub_rn(r.z, c.z); r.w = __fsub_rn(r.w, c.w);
    q.x = __fadd_rn(q.x, c.x); q.y = __fadd_rn(q.y, c.y);
    q.z = __fadd_rn(q.z, c.z); q.w = __fadd_rn(q.w, c.w);
    *(float4*)(resid + o) = r;
    *(float4*)(quant + o) = q;
}

// ---------------- out0 = fl(z + fl(q - z)) transposed; commitment partial ----------------
__global__ __launch_bounds__(256) void k_out0(const float* __restrict__ z,
                                              const float* __restrict__ quant,
                                              float* __restrict__ out0,
                                              double* __restrict__ csum) {
    __shared__ float xt[64][129];
    __shared__ double wsum[4];
    int b = blockIdx.x >> 6, st = blockIdx.x & 63;
    int s0 = st * 64;
    for (int it = 0; it < 8; ++it) {
        int flat = it * 256 + threadIdx.x;
        int sl = flat >> 5, dq = (flat & 31) * 4;
        float4 q = *(const float4*)(quant + (size_t)(b * SLEN + s0 + sl) * D + dq);
        xt[sl][dq] = q.x; xt[sl][dq + 1] = q.y;
        xt[sl][dq + 2] = q.z; xt[sl][dq + 3] = q.w;
    }
    __syncthreads();
    double v = 0.0;
    for (int it = 0; it < 32; ++it) {
        int flat = it * 256 + threadIdx.x;
        int d = flat >> 6, sl = flat & 63;
        size_t o = ((size_t)(b * D + d)) * SLEN + s0 + sl;
        float zz = z[o], qq = xt[sl][d];
        out0[o] = __fadd_rn(zz, __fsub_rn(qq, zz));
        float e = __fsub_rn(zz, qq);
        v += (double)e * (double)e;
    }
    for (int off = 32; off > 0; off >>= 1) v += __shfl_down(v, off, 64);
    int lane = threadIdx.x & 63, wv = threadIdx.x >> 6;
    if (lane == 0) wsum[wv] = v;
    __syncthreads();
    if (threadIdx.x == 0) {
        double tsum = wsum[0] + wsum[1] + wsum[2] + wsum[3];
        atomicAdd(csum, tsum);
    }
}

// ---------------- indices output as float ----------------
__global__ void k_outidx(const int* __restrict__ idx, float* __restrict__ out1) {
    int o = blockIdx.x * blockDim.x + threadIdx.x;   // NPTS*NQ
    int q = o & 7, n = o >> 3;
    out1[o] = (float)idx[q * NPTS + n];
}

// ---------------- histogram ----------------
__global__ void k_hist(const int* __restrict__ idx, int* __restrict__ hist) {
    int o = blockIdx.x * blockDim.x + threadIdx.x;   // NQ*NPTS (layout [q][n])
    int q = o >> 15;
    atomicAdd(&hist[q * KCODES + idx[o]], 1);
}

// ---------------- final scalars ----------------
__global__ __launch_bounds__(256) void k_final(const int* __restrict__ hist,
                                               const double* __restrict__ csum,
                                               float* __restrict__ outs) {
    __shared__ double sh[256];
    double perp = 0.0;
    for (int q = 0; q < NQ; ++q) {
        double h = 0.0;
        for (int k = threadIdx.x; k < KCODES; k += 256) {
            double p = (double)hist[q * KCODES + k] / (double)NPTS;
            h -= p * log(p + 1e-10);
        }
        sh[threadIdx.x] = h; __syncthreads();
        for (int off = 128; off > 0; off >>= 1) {
            if (threadIdx.x < off) sh[threadIdx.x] += sh[threadIdx.x + off];
            __syncthreads();
        }
        if (threadIdx.x == 0) perp += exp(sh[0]);
        __syncthreads();
    }
    if (threadIdx.x == 0) {
        outs[0] = (float)(*csum / (double)((size_t)NPTS * D));
        outs[1] = (float)(perp / (double)NQ);
    }
}

extern "C" void kernel_launch(void* const* d_in, const int* in_sizes, int n_in,
                              void* d_out, int out_size, void* d_ws, size_t ws_size,
                              hipStream_t stream) {
    const float* z  = (const float*)d_in[0];
    const float* cb = (const float*)d_in[1];
    float* out0 = (float*)d_out;                 // 4,194,304 floats [B,D,S]
    float* out1 = out0 + 4194304;                // 262,144 floats  [B,S,Q]
    float* outs = out1 + 262144;                 // 2 scalars

    char* w = (char*)d_ws;
    float* resid  = (float*)w;                           // 16,777,216 B
    float* quant  = (float*)(w + 16777216);              // 16,777,216 B
    int*   idx    = (int*)(w + 33554432);                //  1,048,576 B
    int*   hist   = (int*)(w + 34603008);                //     32,768 B
    double* csum  = (double*)(w + 34635776);             //         64 B
    float* c2f    = (float*)(w + 34635840);              //     32,768 B
    float* pbest  = (float*)(w + 34668608);              //    262,144 B
    int*   pidx   = (int*)(w + 34930752);                //    262,144 B

    k_zero<<<32, 256, 0, stream>>>(hist, csum);
    k_c2<<<32, 256, 0, stream>>>(cb, c2f);
    k_init<<<512, 256, 0, stream>>>(z, resid, quant);

    for (int q = 0; q < NQ; ++q) {
        const float* cbq = cb + (size_t)q * KCODES * D;
        k_argmin<<<2 * NPTS / TM, 256, 0, stream>>>(cbq, c2f + q * KCODES, resid,
                                                    pbest, pidx);
        k_update<<<NPTS * 32 / 256, 256, 0, stream>>>(cbq, pbest, pidx,
                                                      idx + q * NPTS, resid, quant);
    }

    k_out0<<<512, 256, 0, stream>>>(z, quant, out0, csum);
    k_outidx<<<NPTS * NQ / 256, 256, 0, stream>>>(idx, out1);
    k_hist<<<NPTS * NQ / 256, 256, 0, stream>>>(idx, hist);
    k_final<<<1, 256, 0, stream>>>(hist, csum, outs);
}